// Round 4
// baseline (140.997 us; speedup 1.0000x reference)
//
#include <hip/hip_runtime.h>

// GraphAttentionLayer: out = elu( softmax_row( where(adj>0, lrelu(src_i+dst_j), 0) ) @ wh )
// wh = x@w [8192,64]; src = wh@a[:64]; dst = wh@a[64:]
//
// R3 post-mortem: __syncthreads() emits s_waitcnt vmcnt(0) before s_barrier,
// draining the adj prefetch every tile (the m97/m131 structural stall) ->
// k2 stuck at ~2.7 TB/s.
// R4: BARRIER-FREE k2. Each wave owns 16 rows x all 64 features. The MFMA
// A-fragment (row=lane&15, k=(lane>>4)*8+i — layout verified by passing R1-R3)
// is computed per-lane directly from adj/dst registers: P never touches LDS,
// no __syncthreads in the kernel. Register double-buffered adj stream, only
// counted compiler vmcnt waits. src/dst premultiplied by log2e (lrelu commutes
// with positive scale; mask->0 gives exp2(0)=1) so score = add,fmax*mul,sel,v_exp.

constexpr int N_ROWS = 8192;
constexpr int F_IN   = 128;
constexpr int F_OUT  = 64;
#define LRELU_A 0.2f
#define LOG2E   1.4426950408889634f

// workspace layout (bytes)
constexpr size_t OFF_WHT  = 0;                    // 64*8192*2 = 1 MiB bf16 [f][row]
constexpr size_t OFF_SRC  = 1048576;              // 8192 f32 (pre-scaled by log2e)
constexpr size_t OFF_DST  = OFF_SRC + 32768;      // 8192 f32 (pre-scaled by log2e)
constexpr size_t OFF_LP   = OFF_DST + 32768;      // S*8192 f32 (S<=8)
constexpr size_t OFF_ACC  = OFF_LP + 8 * 32768;   // S*8192*64 f32

typedef __attribute__((ext_vector_type(4))) float f32x4;
typedef __attribute__((ext_vector_type(4))) int   i32x4;
typedef __attribute__((ext_vector_type(4))) short s16x4;
typedef __attribute__((ext_vector_type(8))) short s16x8;

union U8 { s16x8 v; unsigned u[4]; };

// pack two positive finite floats to bf16 pair (RNE)
static __device__ __forceinline__ unsigned pk2(float a, float b) {
  unsigned ua = __float_as_uint(a);
  unsigned ub = __float_as_uint(b);
  ua = (ua + 0x7fffu + ((ua >> 16) & 1u)) >> 16;
  ub = (ub + 0x7fffu + ((ub >> 16) & 1u)) & 0xffff0000u;
  return ua | ub;
}

static __device__ __forceinline__ short f2bf(float f) {
  unsigned u = __float_as_uint(f);
  u = (u + 0x7fffu + ((u >> 16) & 1u)) >> 16;
  return (short)u;
}

// ---------------- Kernel 1: wh = x@w ; src/dst (x log2e) ; whT (bf16) -------
// 512 blocks x 256 threads; wave = 4 rows; lane = output feature.
__global__ __launch_bounds__(256) void k1_proj(
    const float* __restrict__ x, const float* __restrict__ w,
    const float* __restrict__ a, short* __restrict__ whT,
    float* __restrict__ src, float* __restrict__ dst)
{
  const int lane = threadIdx.x & 63;   // = output feature f
  const int wid  = threadIdx.x >> 6;
  const int rowBase = blockIdx.x * 16 + wid * 4;   // 4 rows per wave

  float acc[4];
#pragma unroll
  for (int r = 0; r < 4; ++r) acc[r] = 0.0f;

#pragma unroll 1
  for (int kc = 0; kc < 4; ++kc) {     // K chunks of 32 — ONE wreg live
    float wreg[32];
#pragma unroll
    for (int kk = 0; kk < 32; ++kk)
      wreg[kk] = w[(kc * 32 + kk) * F_OUT + lane];   // coalesced
#pragma unroll
    for (int r = 0; r < 4; ++r) {
      const f32x4* xp = (const f32x4*)(x + (size_t)(rowBase + r) * F_IN + kc * 32);
#pragma unroll
      for (int q = 0; q < 8; ++q) {
        f32x4 xv = xp[q];
        acc[r] = fmaf(xv.x, wreg[4*q+0], acc[r]);
        acc[r] = fmaf(xv.y, wreg[4*q+1], acc[r]);
        acc[r] = fmaf(xv.z, wreg[4*q+2], acc[r]);
        acc[r] = fmaf(xv.w, wreg[4*q+3], acc[r]);
      }
    }
  }

  // whT store: lane f's 4 consecutive rows -> one 8B packed store
  s16x4 hb;
#pragma unroll
  for (int r = 0; r < 4; ++r) hb[r] = f2bf(acc[r]);
  *(s16x4*)&whT[(size_t)lane * N_ROWS + rowBase] = hb;

  const float aS = a[lane];
  const float aD = a[F_OUT + lane];
#pragma unroll
  for (int r = 0; r < 4; ++r) {
    float ts = acc[r] * aS;
    float td = acc[r] * aD;
#pragma unroll
    for (int off = 32; off > 0; off >>= 1) {
      ts += __shfl_xor(ts, off, 64);
      td += __shfl_xor(td, off, 64);
    }
    if (lane == 0) {
      src[rowBase + r] = ts * LOG2E;   // log2-domain scores
      dst[rowBase + r] = td * LOG2E;
    }
  }
}

// ---------------- Kernel 2: barrier-free fused mask+exp+PV ----------------
// grid: (N/64, S) x 256 threads (4 waves). Wave owns 16 rows x all 64 feats.
template<int S>
__global__ __launch_bounds__(256, 4) void k2_attn(
    const int* __restrict__ adj, const short* __restrict__ whT,
    const float* __restrict__ src, const float* __restrict__ dst,
    float* __restrict__ acc_part, float* __restrict__ l_part)
{
  constexpr int JLEN = N_ROWS / S;
  constexpr int NI   = JLEN / 64;   // 64-col iterations (even)

  const int lane = threadIdx.x & 63;
  const int wid  = threadIdx.x >> 6;
  const int s    = blockIdx.y;
  const int rowg = blockIdx.x * 64 + wid * 16;
  const int jbase = s * JLEN;
  const int r16  = lane & 15;       // lane's row within the 16-row tile
  const int kq   = lane >> 4;       // k-quad 0..3
  const size_t arow = (size_t)(rowg + r16) * N_ROWS;
  const float sv = src[rowg + r16];              // already * log2e
  const int cb0 = jbase + kq * 8;                // lane col base, iter 0

  f32x4 acc0 = {0,0,0,0}, acc1 = {0,0,0,0}, acc2 = {0,0,0,0}, acc3 = {0,0,0,0};
  float lp = 0.0f;

  i32x4 A0[4], A1[4];
  {  // prologue: iter-0 adj into A0
    const int* p = adj + arow + cb0;
    A0[0] = __builtin_nontemporal_load((const i32x4*)(p));
    A0[1] = __builtin_nontemporal_load((const i32x4*)(p + 4));
    A0[2] = __builtin_nontemporal_load((const i32x4*)(p + 32));
    A0[3] = __builtin_nontemporal_load((const i32x4*)(p + 36));
  }

  auto body = [&](i32x4* CUR, i32x4* NXT, int i) {
    const int c = cb0 + i * 64;
    if (i + 1 < NI) {                 // prefetch next iter's adj (uniform branch)
      const int* p = adj + arow + c + 64;
      NXT[0] = __builtin_nontemporal_load((const i32x4*)(p));
      NXT[1] = __builtin_nontemporal_load((const i32x4*)(p + 4));
      NXT[2] = __builtin_nontemporal_load((const i32x4*)(p + 32));
      NXT[3] = __builtin_nontemporal_load((const i32x4*)(p + 36));
    }
#pragma unroll
    for (int h = 0; h < 2; ++h) {
      const f32x4 dA = *(const f32x4*)(dst + c + h * 32);
      const f32x4 dB = *(const f32x4*)(dst + c + h * 32 + 4);
      const i32x4 aA = CUR[2 * h];
      const i32x4 aB = CUR[2 * h + 1];
      float p0, p1, p2, p3, p4, p5, p6, p7;
#define PE(pp, dd, aa) { float e = sv + (dd); e = fmaxf(e, LRELU_A * e); \
                         (pp) = ((aa) > 0) ? __builtin_amdgcn_exp2f(e) : 1.0f; }
      PE(p0, dA.x, aA.x) PE(p1, dA.y, aA.y) PE(p2, dA.z, aA.z) PE(p3, dA.w, aA.w)
      PE(p4, dB.x, aB.x) PE(p5, dB.y, aB.y) PE(p6, dB.z, aB.z) PE(p7, dB.w, aB.w)
#undef PE
      lp += ((p0 + p1) + (p2 + p3)) + ((p4 + p5) + (p6 + p7));
      U8 u;
      u.u[0] = pk2(p0, p1); u.u[1] = pk2(p2, p3);
      u.u[2] = pk2(p4, p5); u.u[3] = pk2(p6, p7);
      // B fragments: whT[feature][col], col = c + h*32 (+k within via lane)
      const short* bp = whT + (size_t)r16 * N_ROWS + (c + h * 32);
      const s16x8 b0 = *(const s16x8*)(bp);
      const s16x8 b1 = *(const s16x8*)(bp + (size_t)16 * N_ROWS);
      const s16x8 b2 = *(const s16x8*)(bp + (size_t)32 * N_ROWS);
      const s16x8 b3 = *(const s16x8*)(bp + (size_t)48 * N_ROWS);
      acc0 = __builtin_amdgcn_mfma_f32_16x16x32_bf16(u.v, b0, acc0, 0, 0, 0);
      acc1 = __builtin_amdgcn_mfma_f32_16x16x32_bf16(u.v, b1, acc1, 0, 0, 0);
      acc2 = __builtin_amdgcn_mfma_f32_16x16x32_bf16(u.v, b2, acc2, 0, 0, 0);
      acc3 = __builtin_amdgcn_mfma_f32_16x16x32_bf16(u.v, b3, acc3, 0, 0, 0);
    }
  };

  for (int i = 0; i < NI; i += 2) {   // manual double-buffer, static reg names
    body(A0, A1, i);
    body(A1, A0, i + 1);
  }

  // ---- epilogue ----
  // row-sum: lanes {l, l^16, l^32, l^48} hold same row's partials
  lp += __shfl_xor(lp, 16, 64);
  lp += __shfl_xor(lp, 32, 64);
  if (lane < 16) l_part[(size_t)s * N_ROWS + rowg + lane] = lp;

  // C/D layout: col(feature offset) = lane&15, row = (lane>>4)*4 + reg
#define STORE_ACC(av, nt) _Pragma("unroll") \
  for (int rg = 0; rg < 4; ++rg) { \
    const int row = rowg + kq * 4 + rg; \
    __builtin_nontemporal_store((av)[rg], \
        acc_part + ((size_t)s * N_ROWS + row) * F_OUT + (nt) * 16 + r16); \
  }
  STORE_ACC(acc0, 0) STORE_ACC(acc1, 1) STORE_ACC(acc2, 2) STORE_ACC(acc3, 3)
#undef STORE_ACC
}

// ---------------- Kernel 3: combine partials, normalize, ELU ----------------
template<int S>
__global__ __launch_bounds__(256) void k3_combine(
    const float* __restrict__ acc_part, const float* __restrict__ l_part,
    float* __restrict__ out)
{
  const int idx = blockIdx.x * 256 + threadIdx.x;  // over N*F/4
  const int row = idx >> 4;          // F_OUT/4 = 16
  const int f4  = idx & 15;
  f32x4 h = {0.f, 0.f, 0.f, 0.f};
  float l = 0.f;
#pragma unroll
  for (int s = 0; s < S; ++s) {
    h += *(const f32x4*)(acc_part + ((size_t)s * N_ROWS + row) * F_OUT + 4 * f4);
    l += l_part[(size_t)s * N_ROWS + row];
  }
  const float inv = 1.0f / l;
  f32x4 o;
  {
    float v0 = h.x * inv; o.x = v0 > 0.f ? v0 : (__expf(v0) - 1.0f);
    float v1 = h.y * inv; o.y = v1 > 0.f ? v1 : (__expf(v1) - 1.0f);
    float v2 = h.z * inv; o.z = v2 > 0.f ? v2 : (__expf(v2) - 1.0f);
    float v3 = h.w * inv; o.w = v3 > 0.f ? v3 : (__expf(v3) - 1.0f);
  }
  *(f32x4*)(out + (size_t)row * F_OUT + 4 * f4) = o;
}

// ---------------- launch ----------------
extern "C" void kernel_launch(void* const* d_in, const int* in_sizes, int n_in,
                              void* d_out, int out_size, void* d_ws, size_t ws_size,
                              hipStream_t stream) {
  const float* x   = (const float*)d_in[0];
  const int*   adj = (const int*)d_in[1];
  const float* w   = (const float*)d_in[2];
  const float* a   = (const float*)d_in[3];
  float* out = (float*)d_out;
  char* ws = (char*)d_ws;

  short* whT      = (short*)(ws + OFF_WHT);
  float* src      = (float*)(ws + OFF_SRC);
  float* dst      = (float*)(ws + OFF_DST);
  float* l_part   = (float*)(ws + OFF_LP);
  float* acc_part = (float*)(ws + OFF_ACC);

  k1_proj<<<N_ROWS / 16, 256, 0, stream>>>(x, w, a, whT, src, dst);

  if (ws_size >= OFF_ACC + 8ull * N_ROWS * F_OUT * 4) {
    k2_attn<8><<<dim3(N_ROWS / 64, 8), 256, 0, stream>>>(adj, whT, src, dst,
                                                         acc_part, l_part);
    k3_combine<8><<<(N_ROWS * F_OUT / 4) / 256, 256, 0, stream>>>(acc_part, l_part, out);
  } else {
    k2_attn<2><<<dim3(N_ROWS / 64, 2), 256, 0, stream>>>(adj, whT, src, dst,
                                                         acc_part, l_part);
    k3_combine<2><<<(N_ROWS * F_OUT / 4) / 256, 256, 0, stream>>>(acc_part, l_part, out);
  }
}

// Round 5
// 127.084 us; speedup vs baseline: 1.1095x; 1.1095x over previous
//
#include <hip/hip_runtime.h>
#include <hip/hip_bf16.h>

// GraphAttentionLayer: out = elu( softmax_row( where(adj>0, lrelu(src_i+dst_j), 0) ) @ wh )
// wh = x@w [8192,64]; src = wh@a[:64]; dst = wh@a[64:]
//
// R4 post-mortem: B (whT) fragments were loaded inside iter i AFTER the adj
// prefetch for i+1 — vmcnt is a counter, so waiting for B == vmcnt(0) ==
// draining the prefetch every iter (same stall as R3's barrier, relocated).
// R5: strict pipeline discipline. Per iter: issue[B(i+1) x8 + adj(i+1) x4]
// FIRST, then compute iter i from registers (waits leave next-iter loads in
// flight). dst moved to LDS (lgkmcnt stream, one barrier before the loop).
// bf16 pack via __float2bfloat16 (v_cvt_pk). launch_bounds(256,3).

constexpr int N_ROWS = 8192;
constexpr int F_IN   = 128;
constexpr int F_OUT  = 64;
#define LRELU_A 0.2f
#define LOG2E   1.4426950408889634f

// workspace layout (bytes)
constexpr size_t OFF_WHT  = 0;                    // 64*8192*2 = 1 MiB bf16 [f][row]
constexpr size_t OFF_SRC  = 1048576;              // 8192 f32 (pre-scaled by log2e)
constexpr size_t OFF_DST  = OFF_SRC + 32768;      // 8192 f32 (pre-scaled by log2e)
constexpr size_t OFF_LP   = OFF_DST + 32768;      // S*8192 f32 (S<=8)
constexpr size_t OFF_ACC  = OFF_LP + 8 * 32768;   // S*8192*64 f32

typedef __attribute__((ext_vector_type(4))) float f32x4;
typedef __attribute__((ext_vector_type(4))) int   i32x4;
typedef __attribute__((ext_vector_type(4))) short s16x4;
typedef __attribute__((ext_vector_type(8))) short s16x8;

static __device__ __forceinline__ short f2bf(float f) {
  unsigned u = __float_as_uint(f);
  u = (u + 0x7fffu + ((u >> 16) & 1u)) >> 16;  // RNE
  return (short)u;
}

// ---------------- Kernel 1: wh = x@w ; src/dst (x log2e) ; whT (bf16) -------
// 256 blocks x 256 threads; wave = 8 rows; lane = output feature.
__global__ __launch_bounds__(256) void k1_proj(
    const float* __restrict__ x, const float* __restrict__ w,
    const float* __restrict__ a, short* __restrict__ whT,
    float* __restrict__ src, float* __restrict__ dst)
{
  const int lane = threadIdx.x & 63;   // = output feature f
  const int wid  = threadIdx.x >> 6;
  const int rowBase = blockIdx.x * 32 + wid * 8;   // 8 rows per wave

  float acc[8];
#pragma unroll
  for (int r = 0; r < 8; ++r) acc[r] = 0.0f;

#pragma unroll 1
  for (int kc = 0; kc < 4; ++kc) {     // K chunks of 32 — ONE wreg live
    float wreg[32];
#pragma unroll
    for (int kk = 0; kk < 32; ++kk)
      wreg[kk] = w[(kc * 32 + kk) * F_OUT + lane];   // coalesced
#pragma unroll
    for (int r = 0; r < 8; ++r) {
      const f32x4* xp = (const f32x4*)(x + (size_t)(rowBase + r) * F_IN + kc * 32);
#pragma unroll
      for (int q = 0; q < 8; ++q) {    // wave-uniform broadcast loads
        f32x4 xv = xp[q];
        acc[r] = fmaf(xv.x, wreg[4*q+0], acc[r]);
        acc[r] = fmaf(xv.y, wreg[4*q+1], acc[r]);
        acc[r] = fmaf(xv.z, wreg[4*q+2], acc[r]);
        acc[r] = fmaf(xv.w, wreg[4*q+3], acc[r]);
      }
    }
  }

  // whT store: lane f's 8 consecutive rows -> one 16B packed store
  s16x8 hb;
#pragma unroll
  for (int r = 0; r < 8; ++r) hb[r] = f2bf(acc[r]);
  *(s16x8*)&whT[(size_t)lane * N_ROWS + rowBase] = hb;

  const float aS = a[lane];
  const float aD = a[F_OUT + lane];
#pragma unroll
  for (int r = 0; r < 8; ++r) {
    float ts = acc[r] * aS;
    float td = acc[r] * aD;
#pragma unroll
    for (int off = 32; off > 0; off >>= 1) {
      ts += __shfl_xor(ts, off, 64);
      td += __shfl_xor(td, off, 64);
    }
    if (lane == 0) {
      src[rowBase + r] = ts * LOG2E;   // log2-domain scores
      dst[rowBase + r] = td * LOG2E;
    }
  }
}

// ---------------- Kernel 2: pipelined barrier-free fused mask+exp+PV --------
// grid: (N/64, S) x 256 threads (4 waves). Wave owns 16 rows x all 64 feats.
// A-fragment computed per-lane in registers (row=lane&15, k=(lane>>4)*8+j).
template<int S>
__global__ __launch_bounds__(256, 3) void k2_attn(
    const int* __restrict__ adj, const short* __restrict__ whT,
    const float* __restrict__ src, const float* __restrict__ dst,
    float* __restrict__ acc_part, float* __restrict__ l_part)
{
  constexpr int JLEN = N_ROWS / S;
  constexpr int NI   = JLEN / 64;   // 64-col iterations (even)
  __shared__ float Dlds[JLEN];

  const int lane = threadIdx.x & 63;
  const int wid  = threadIdx.x >> 6;
  const int s    = blockIdx.y;
  const int jbase = s * JLEN;
  const int rowg = blockIdx.x * 64 + wid * 16;
  const int r16  = lane & 15;       // row within wave tile / B feature-in-tile
  const int kq   = lane >> 4;       // k-quad 0..3

  // stage dst slice (lgkmcnt stream). ONE barrier, before the pipeline starts.
  for (int t = threadIdx.x * 4; t < JLEN; t += 1024)
    *(f32x4*)&Dlds[t] = *(const f32x4*)(dst + jbase + t);
  __syncthreads();

  const size_t arow = (size_t)(rowg + r16) * N_ROWS;
  const float sv = src[rowg + r16];               // already * log2e
  const int cb0 = jbase + kq * 8;                 // lane col base, iter 0
  const short* bbase = whT + (size_t)r16 * N_ROWS;

  f32x4 acc0 = {0,0,0,0}, acc1 = {0,0,0,0}, acc2 = {0,0,0,0}, acc3 = {0,0,0,0};
  float lp = 0.0f;

  i32x4 Aa[4], Ab[4];       // adj double-buffer
  s16x8 Ba[8], Bb[8];       // whT fragment double-buffer [h*4 + ftile]

  auto issue = [&](i32x4* A, s16x8* B, int i) {
    const int c = cb0 + i * 64;
    const short* bq = bbase + c;
#pragma unroll
    for (int f = 0; f < 4; ++f) {          // h=0 frags then h=1 frags
      B[f]     = *(const s16x8*)(bq + (size_t)f * 16 * N_ROWS);
      B[4 + f] = *(const s16x8*)(bq + (size_t)f * 16 * N_ROWS + 32);
    }
    const int* p = adj + arow + c;
    A[0] = __builtin_nontemporal_load((const i32x4*)(p));
    A[1] = __builtin_nontemporal_load((const i32x4*)(p + 4));
    A[2] = __builtin_nontemporal_load((const i32x4*)(p + 32));
    A[3] = __builtin_nontemporal_load((const i32x4*)(p + 36));
  };

  auto compute = [&](const i32x4* A, const s16x8* B, int i) {
    const int db = kq * 8 + i * 64;
#pragma unroll
    for (int h = 0; h < 2; ++h) {
      const f32x4 dA = *(const f32x4*)&Dlds[db + h * 32];
      const f32x4 dB = *(const f32x4*)&Dlds[db + h * 32 + 4];
      const i32x4 aA = A[2 * h];
      const i32x4 aB = A[2 * h + 1];
      float p0, p1, p2, p3, p4, p5, p6, p7;
#define PE(pp, dd, aa) { float e = sv + (dd); e = fmaxf(e, LRELU_A * e); \
                         (pp) = ((aa) > 0) ? __builtin_amdgcn_exp2f(e) : 1.0f; }
      PE(p0, dA.x, aA.x) PE(p1, dA.y, aA.y) PE(p2, dA.z, aA.z) PE(p3, dA.w, aA.w)
      PE(p4, dB.x, aB.x) PE(p5, dB.y, aB.y) PE(p6, dB.z, aB.z) PE(p7, dB.w, aB.w)
#undef PE
      lp += ((p0 + p1) + (p2 + p3)) + ((p4 + p5) + (p6 + p7));
      union { s16x8 v; __hip_bfloat16 b[8]; } u;
      u.b[0] = __float2bfloat16(p0); u.b[1] = __float2bfloat16(p1);
      u.b[2] = __float2bfloat16(p2); u.b[3] = __float2bfloat16(p3);
      u.b[4] = __float2bfloat16(p4); u.b[5] = __float2bfloat16(p5);
      u.b[6] = __float2bfloat16(p6); u.b[7] = __float2bfloat16(p7);
      acc0 = __builtin_amdgcn_mfma_f32_16x16x32_bf16(u.v, B[h * 4 + 0], acc0, 0, 0, 0);
      acc1 = __builtin_amdgcn_mfma_f32_16x16x32_bf16(u.v, B[h * 4 + 1], acc1, 0, 0, 0);
      acc2 = __builtin_amdgcn_mfma_f32_16x16x32_bf16(u.v, B[h * 4 + 2], acc2, 0, 0, 0);
      acc3 = __builtin_amdgcn_mfma_f32_16x16x32_bf16(u.v, B[h * 4 + 3], acc3, 0, 0, 0);
    }
  };

  issue(Aa, Ba, 0);                 // prologue
#pragma unroll 1
  for (int i = 0; i < NI; i += 2) { // static buffer names (no runtime indexing)
    if (i + 1 < NI) issue(Ab, Bb, i + 1);
    compute(Aa, Ba, i);             // waits leave iter i+1 loads in flight
    if (i + 2 < NI) issue(Aa, Ba, i + 2);
    compute(Ab, Bb, i + 1);
  }

  // ---- epilogue ----
  lp += __shfl_xor(lp, 16, 64);     // lanes {l, l^16, l^32, l^48}: same row
  lp += __shfl_xor(lp, 32, 64);
  if (lane < 16) l_part[(size_t)s * N_ROWS + rowg + lane] = lp;

  // C/D layout: col(feature offset) = lane&15, row = (lane>>4)*4 + reg
#define STORE_ACC(av, nt) _Pragma("unroll") \
  for (int rg = 0; rg < 4; ++rg) { \
    const int row = rowg + kq * 4 + rg; \
    __builtin_nontemporal_store((av)[rg], \
        acc_part + ((size_t)s * N_ROWS + row) * F_OUT + (nt) * 16 + r16); \
  }
  STORE_ACC(acc0, 0) STORE_ACC(acc1, 1) STORE_ACC(acc2, 2) STORE_ACC(acc3, 3)
#undef STORE_ACC
}

// ---------------- Kernel 3: combine partials, normalize, ELU ----------------
template<int S>
__global__ __launch_bounds__(256) void k3_combine(
    const float* __restrict__ acc_part, const float* __restrict__ l_part,
    float* __restrict__ out)
{
  const int idx = blockIdx.x * 256 + threadIdx.x;  // over N*F/4
  const int row = idx >> 4;          // F_OUT/4 = 16
  const int f4  = idx & 15;
  f32x4 h = {0.f, 0.f, 0.f, 0.f};
  float l = 0.f;
#pragma unroll
  for (int s = 0; s < S; ++s) {
    h += *(const f32x4*)(acc_part + ((size_t)s * N_ROWS + row) * F_OUT + 4 * f4);
    l += l_part[(size_t)s * N_ROWS + row];
  }
  const float inv = 1.0f / l;
  f32x4 o;
  {
    float v0 = h.x * inv; o.x = v0 > 0.f ? v0 : (__expf(v0) - 1.0f);
    float v1 = h.y * inv; o.y = v1 > 0.f ? v1 : (__expf(v1) - 1.0f);
    float v2 = h.z * inv; o.z = v2 > 0.f ? v2 : (__expf(v2) - 1.0f);
    float v3 = h.w * inv; o.w = v3 > 0.f ? v3 : (__expf(v3) - 1.0f);
  }
  *(f32x4*)(out + (size_t)row * F_OUT + 4 * f4) = o;
}

// ---------------- launch ----------------
extern "C" void kernel_launch(void* const* d_in, const int* in_sizes, int n_in,
                              void* d_out, int out_size, void* d_ws, size_t ws_size,
                              hipStream_t stream) {
  const float* x   = (const float*)d_in[0];
  const int*   adj = (const int*)d_in[1];
  const float* w   = (const float*)d_in[2];
  const float* a   = (const float*)d_in[3];
  float* out = (float*)d_out;
  char* ws = (char*)d_ws;

  short* whT      = (short*)(ws + OFF_WHT);
  float* src      = (float*)(ws + OFF_SRC);
  float* dst      = (float*)(ws + OFF_DST);
  float* l_part   = (float*)(ws + OFF_LP);
  float* acc_part = (float*)(ws + OFF_ACC);

  k1_proj<<<N_ROWS / 32, 256, 0, stream>>>(x, w, a, whT, src, dst);

  if (ws_size >= OFF_ACC + 8ull * N_ROWS * F_OUT * 4) {
    k2_attn<8><<<dim3(N_ROWS / 64, 8), 256, 0, stream>>>(adj, whT, src, dst,
                                                         acc_part, l_part);
    k3_combine<8><<<(N_ROWS * F_OUT / 4) / 256, 256, 0, stream>>>(acc_part, l_part, out);
  } else {
    k2_attn<2><<<dim3(N_ROWS / 64, 2), 256, 0, stream>>>(adj, whT, src, dst,
                                                         acc_part, l_part);
    k3_combine<2><<<(N_ROWS * F_OUT / 4) / 256, 256, 0, stream>>>(acc_part, l_part, out);
  }
}